// Round 12
// baseline (303.857 us; speedup 1.0000x reference)
//
#include <hip/hip_runtime.h>

// GCN forward: conv1(GEMM + sym-norm agg) -> BN -> PReLU -> conv2(GEMM + agg)
// N=100000, E=1600000, DIN=128, 2H=128, H=64. fp32 in/out.
//
// R15 changes vs R14 (295.0):
//  - agg1 split into two half-range dispatches (~30 us each): diagnostic —
//    surfaces the true #2 kernel in rocprof top-5 (was saturated by agg1
//    replicas). No algorithmic change.
//  - bnstats: grid 1024 -> 2048, 8 interleaved bnacc copies (contention/addr
//    unchanged); gemm2 bnfinal sums 8 copies.
// R14 keepers: packed uint pairs + LDS-staged bucket_k, 1-wave-per-node aggs
// with 16/8/4/1 gather tiers, int2 rowspan, bf16 z, fused binpass+wprep,
// swizzled bf16 W tables, MFMA split-precision GEMMs, fused bnfinal, dinv
// pre-scaling, NT stores.

#define DIN 128
#define F1  128   // 2H
#define F2  64    // H
#define BN_EPS 1e-5f
#define NODE_BSHIFT 8          // 256 nodes per bucket
#define NODE_BMASK  255
#define CHUNK 8192             // edges per binpass block
#define PADB 4608              // padded edges per bucket (mean 4096 + 8 sigma)

typedef __attribute__((ext_vector_type(8))) short bf16x8;
typedef __attribute__((ext_vector_type(8))) unsigned short u16x8;
typedef __attribute__((ext_vector_type(4))) float f32x4;
typedef __attribute__((ext_vector_type(2))) float f32x2;

__device__ __forceinline__ unsigned short f2bf(float f) {
    unsigned int u = __float_as_uint(f);
    u = u + 0x7fffu + ((u >> 16) & 1u);   // RNE
    return (unsigned short)(u >> 16);
}
__device__ __forceinline__ float bf2f(unsigned short u) { return __uint_as_float((unsigned int)u << 16); }
__device__ __forceinline__ float bf_lo(unsigned int v) { return __uint_as_float(v << 16); }
__device__ __forceinline__ float bf_hi(unsigned int v) { return __uint_as_float(v & 0xffff0000u); }

// ---------------- graph build + W prep (fused) ----------------
// blocks [0,eb): block counting-sort of 8192-edge chunks into padded
// per-bucket regions (count-based cursors, bucketcnt pre-zeroed).
// pairs entry: src | (dst&255)<<24  (src < 2^17).
// blocks [eb,eb+12): W1/W2 -> swizzled transposed bf16 hi/lo tables.
// addr(c,k) = c*128 + ((k>>3)^(c&15))*8 + (k&7)   (ushort units)

__global__ __launch_bounds__(256) void binpass_k(const int* __restrict__ src,
                                                 const int* __restrict__ dst,
                                                 int* __restrict__ bucketcnt,
                                                 unsigned int* __restrict__ pairs, int e, int eb,
                                                 const float* __restrict__ W1,
                                                 const float* __restrict__ W2,
                                                 unsigned short* __restrict__ wt1h,
                                                 unsigned short* __restrict__ wt1l,
                                                 unsigned short* __restrict__ wt2h,
                                                 unsigned short* __restrict__ wt2l) {
    if (blockIdx.x >= eb) {   // ---- wprep tail blocks ----
        int t = (blockIdx.x - eb) * 256 + threadIdx.x;
        if (t < 2048) {                 // W1: 128 cols x 16 k-octets
            int c = t >> 4, k8 = (t & 15) * 8;
            u16x8 hv, lv;
#pragma unroll
            for (int j = 0; j < 8; j++) {
                float v = W1[(size_t)(k8 + j) * 128 + c];
                unsigned short hi = f2bf(v);
                hv[j] = hi;
                lv[j] = f2bf(v - bf2f(hi));
            }
            int addr = c * 128 + (((k8 >> 3) ^ (c & 15)) << 3);
            *(u16x8*)&wt1h[addr] = hv;
            *(u16x8*)&wt1l[addr] = lv;
        } else if (t < 3072) {          // W2: 64 cols x 16 k-octets
            int tt = t - 2048;
            int c = tt >> 4, k8 = (tt & 15) * 8;
            u16x8 hv, lv;
#pragma unroll
            for (int j = 0; j < 8; j++) {
                float v = W2[(size_t)(k8 + j) * 64 + c];
                unsigned short hi = f2bf(v);
                hv[j] = hi;
                lv[j] = f2bf(v - bf2f(hi));
            }
            int addr = c * 128 + (((k8 >> 3) ^ (c & 15)) << 3);
            *(u16x8*)&wt2h[addr] = hv;
            *(u16x8*)&wt2l[addr] = lv;
        }
        return;
    }
    // ---- binpass body ----
    __shared__ int lh[512], lbase[512], lrank[512];
    int t = threadIdx.x;
    for (int i = t; i < 512; i += 256) { lh[i] = 0; lrank[i] = 0; }
    __syncthreads();
    int base = blockIdx.x * CHUNK;
    int end = base + CHUNK; if (end > e) end = e;
    for (int i = base + t; i < end; i += 256)
        atomicAdd(&lh[dst[i] >> NODE_BSHIFT], 1);
    __syncthreads();
    for (int b = t; b < 512; b += 256) {
        int v = lh[b];
        lbase[b] = v ? (b * PADB + atomicAdd(&bucketcnt[b], v)) : 0;
    }
    __syncthreads();
    for (int i = base + t; i < end; i += 256) {
        int sv = src[i], dv = dst[i];
        int b = dv >> NODE_BSHIFT;
        int r = atomicAdd(&lrank[b], 1);
        int idx = lbase[b] + r;
        if (idx < (b + 1) * PADB)
            pairs[idx] = (unsigned int)sv | ((unsigned int)(dv & NODE_BMASK) << 24);
    }
}

// one block per bucket: LDS-stage packed pairs, per-node degree -> dinv +
// rowspan, fine scatter from LDS.

__global__ __launch_bounds__(256) void bucket_k(const unsigned int* __restrict__ pairs,
                                                const int* __restrict__ bucketcnt,
                                                float* __restrict__ dinv,
                                                int2* __restrict__ rowspan,
                                                int* __restrict__ srcsorted, int n) {
    __shared__ unsigned int lp[PADB];          // 18.4 KB packed pairs
    __shared__ int lh[256], loff[256], lrank[256];
    int b = blockIdx.x, t = threadIdx.x;
    int e0 = b * PADB;
    int cnt = bucketcnt[b];
    lh[t] = 0;
    lrank[t] = 0;
    __syncthreads();
    for (int i = t; i < cnt; i += 256) {
        unsigned int p = pairs[e0 + i];
        lp[i] = p;
        atomicAdd(&lh[p >> 24], 1);
    }
    __syncthreads();
    int deg = lh[t];
    int run = deg;
    for (int ofs = 1; ofs < 256; ofs <<= 1) {
        int y = (t >= ofs) ? lh[t - ofs] : 0;
        __syncthreads();
        run += y;
        lh[t] = run;
        __syncthreads();
    }
    loff[t] = run - deg;
    int node = (b << NODE_BSHIFT) + t;
    if (node < n) {
        dinv[node] = rsqrtf((float)(deg + 1));   // +1 self-loop
        rowspan[node] = make_int2(e0 + (run - deg), e0 + run);
    }
    __syncthreads();
    for (int i = t; i < cnt; i += 256) {
        unsigned int p = lp[i];
        int lo = p >> 24;
        int r = atomicAdd(&lrank[lo], 1);
        srcsorted[e0 + loff[lo] + r] = (int)(p & 0x00FFFFFFu);
    }
}

// ---- GEMM1 (MFMA): h'(bf16) = dinv * (x @ W1), split precision ----
// 128 rows/block, 512 threads (8 waves of 16 rows x 128 cols).

__global__ __launch_bounds__(512) void gemm1_k(const float* __restrict__ x,
                                               const unsigned short* __restrict__ wt1h,
                                               const unsigned short* __restrict__ wt1l,
                                               const float* __restrict__ dinv,
                                               unsigned int* __restrict__ h, int n) {
    __shared__ unsigned short wh[128 * 128];   // W^T hi, swizzled (prebuilt layout)
    __shared__ unsigned short wl[128 * 128];   // W^T lo
    int t = threadIdx.x;
    {   // linear conflict-free staging copy (L2-hot source)
        const uint4* gh = (const uint4*)wt1h;
        const uint4* gl = (const uint4*)wt1l;
        uint4* dh = (uint4*)wh;
        uint4* dl = (uint4*)wl;
        for (int i = t; i < 2048; i += 512) { dh[i] = gh[i]; dl[i] = gl[i]; }
    }
    __syncthreads();

    int w = t >> 6, l = t & 63;
    int lr = l & 15, lg = l >> 4;
    int rowbase = blockIdx.x * 128;
    int arow = rowbase + w * 16 + lr;
    if (arow >= n) arow = n - 1;

    f32x4 acc[8];
#pragma unroll
    for (int nt = 0; nt < 8; nt++) acc[nt] = (f32x4)(0.0f);

#pragma unroll
    for (int ks = 0; ks < 4; ks++) {
        const float4* ap = (const float4*)(x + (size_t)arow * 128 + ks * 32 + lg * 8);
        float4 v0 = ap[0], v1 = ap[1];
        float vv[8] = {v0.x, v0.y, v0.z, v0.w, v1.x, v1.y, v1.z, v1.w};
        bf16x8 ah, al;
#pragma unroll
        for (int j = 0; j < 8; j++) {
            unsigned short hi = f2bf(vv[j]);
            ah[j] = (short)hi;
            al[j] = (short)f2bf(vv[j] - bf2f(hi));
        }
#pragma unroll
        for (int nt = 0; nt < 8; nt++) {
            int ao = (nt * 16 + lr) * 128 + (((4 * ks + lg) ^ lr) << 3);
            bf16x8 bh = *(const bf16x8*)&wh[ao];
            bf16x8 bl = *(const bf16x8*)&wl[ao];
            acc[nt] = __builtin_amdgcn_mfma_f32_16x16x32_bf16(ah, bh, acc[nt], 0, 0, 0);
            acc[nt] = __builtin_amdgcn_mfma_f32_16x16x32_bf16(al, bh, acc[nt], 0, 0, 0);
            acc[nt] = __builtin_amdgcn_mfma_f32_16x16x32_bf16(ah, bl, acc[nt], 0, 0, 0);
        }
    }
    __syncthreads();                       // all waves done reading W
    unsigned short* ob = wh;               // reuse as [128][128] bf16 bounce
#pragma unroll
    for (int r = 0; r < 4; r++) {
        int rl = w * 16 + lg * 4 + r;      // C row = (lane>>4)*4 + reg
        int grow = rowbase + rl;
        float di = dinv[grow < n ? grow : 0];
#pragma unroll
        for (int nt = 0; nt < 8; nt++)
            ob[rl * 128 + nt * 16 + lr] = f2bf(acc[nt][r] * di);
    }
    __syncthreads();
    const unsigned int* ob32 = (const unsigned int*)ob;
    for (int i = t; i < 128 * 64; i += 512) {
        int rl = i >> 6, cu = i & 63;
        int grow = rowbase + rl;
        if (grow < n) h[(size_t)grow * 64 + cu] = ob32[rl * 64 + cu];
    }
}

// -------- aggregation 1: z(bf16) = dinv_d * (sum h'_s + h'_d) + b1 --------
// 1 wave/node, 64 lanes x 4B/lane row gather; 16/8/4/1 batched tiers.
// Launched as two half-range dispatches (diagnostic: unmasks #2 kernel).

__global__ __launch_bounds__(64) void agg1_k(const unsigned int* __restrict__ h,  // bf16x2, 64/row
                                             const float* __restrict__ dinv,
                                             const int2* __restrict__ rowspan,
                                             const int* __restrict__ srcs,
                                             const float* __restrict__ b1,
                                             unsigned int* __restrict__ z, int nd0) {
    int nd = nd0 + blockIdx.x;
    int f = threadIdx.x;  // bf16-pair index, 0..63
    float di = dinv[nd];
    unsigned int sv = h[(size_t)nd * 64 + f];
    float ax = bf_lo(sv);
    float ay = bf_hi(sv);
    int2 span = rowspan[nd];
    int e = span.x, e1 = span.y;
    for (; e + 16 <= e1; e += 16) {
        int s[16];
#pragma unroll
        for (int j = 0; j < 16; j++) s[j] = srcs[e + j];
        unsigned int v[16];
#pragma unroll
        for (int j = 0; j < 16; j++) v[j] = h[(size_t)s[j] * 64 + f];
#pragma unroll
        for (int j = 0; j < 16; j++) { ax += bf_lo(v[j]); ay += bf_hi(v[j]); }
    }
    for (; e + 8 <= e1; e += 8) {
        int s[8];
#pragma unroll
        for (int j = 0; j < 8; j++) s[j] = srcs[e + j];
        unsigned int v[8];
#pragma unroll
        for (int j = 0; j < 8; j++) v[j] = h[(size_t)s[j] * 64 + f];
#pragma unroll
        for (int j = 0; j < 8; j++) { ax += bf_lo(v[j]); ay += bf_hi(v[j]); }
    }
    for (; e + 4 <= e1; e += 4) {
        int s[4];
#pragma unroll
        for (int j = 0; j < 4; j++) s[j] = srcs[e + j];
        unsigned int v[4];
#pragma unroll
        for (int j = 0; j < 4; j++) v[j] = h[(size_t)s[j] * 64 + f];
#pragma unroll
        for (int j = 0; j < 4; j++) { ax += bf_lo(v[j]); ay += bf_hi(v[j]); }
    }
    for (; e < e1; e++) {
        unsigned int v = h[(size_t)srcs[e] * 64 + f];
        ax += bf_lo(v);
        ay += bf_hi(v);
    }
    float2 bb = ((const float2*)b1)[f];
    float ox = fmaf(ax, di, bb.x);
    float oy = fmaf(ay, di, bb.y);
    unsigned int zu = (unsigned int)f2bf(ox) | ((unsigned int)f2bf(oy) << 16);
    __builtin_nontemporal_store(zu, z + (size_t)nd * 64 + f);
}

// ---------------- BatchNorm stats (bf16 z input) ----------------
// 2048 blocks; 8 interleaved bnacc copies.

__global__ __launch_bounds__(256) void bnstats_k(const unsigned int* __restrict__ zb,
                                                 double* __restrict__ bnacc, int n) {
    __shared__ float reds[8][128];
    __shared__ float redq[8][128];
    int t = threadIdx.x;
    int q = t >> 5;          // row lane 0..7
    int c = t & 31;          // uint2 column (4 feats)
    const uint2* z2 = (const uint2*)zb;
    float s0 = 0.f, s1 = 0.f, s2 = 0.f, s3 = 0.f;
    float q0 = 0.f, q1 = 0.f, q2 = 0.f, q3 = 0.f;
    int stride = gridDim.x * 8;
#pragma unroll 2
    for (int r = blockIdx.x * 8 + q; r < n; r += stride) {
        uint2 v = z2[(size_t)r * 32 + c];
        float a = bf_lo(v.x), b = bf_hi(v.x), cc = bf_lo(v.y), d = bf_hi(v.y);
        s0 += a; s1 += b; s2 += cc; s3 += d;
        q0 = fmaf(a, a, q0);
        q1 = fmaf(b, b, q1);
        q2 = fmaf(cc, cc, q2);
        q3 = fmaf(d, d, q3);
    }
    reds[q][c * 4]     = s0; redq[q][c * 4]     = q0;
    reds[q][c * 4 + 1] = s1; redq[q][c * 4 + 1] = q1;
    reds[q][c * 4 + 2] = s2; redq[q][c * 4 + 2] = q2;
    reds[q][c * 4 + 3] = s3; redq[q][c * 4 + 3] = q3;
    __syncthreads();
    if (t < 128) {
        float ssum = 0.f, qsum = 0.f;
#pragma unroll
        for (int i = 0; i < 8; i++) {
            ssum += reds[i][t];
            qsum += redq[i][t];
        }
        int copy = (blockIdx.x & 7) * 256;
        atomicAdd(&bnacc[copy + t], (double)ssum);
        atomicAdd(&bnacc[copy + 128 + t], (double)qsum);
    }
}

// ---- GEMM2 (MFMA): h2'(bf16) = dinv * (prelu(bn(z)) @ W2), bnfinal fused ----
// z input bf16 (uint = 2 feats); BN/PReLU in fp32; full hi/lo MFMA split.

__global__ __launch_bounds__(512) void gemm2_k(const unsigned int* __restrict__ zb,
                                               const unsigned short* __restrict__ wt2h,
                                               const unsigned short* __restrict__ wt2l,
                                               const double* __restrict__ bnacc, // 8 copies x 256
                                               const float* __restrict__ gamma,
                                               const float* __restrict__ beta,
                                               const float* __restrict__ prelu_a,
                                               const float* __restrict__ dinv,
                                               unsigned int* __restrict__ h2, int n) {
    __shared__ unsigned short wh[64 * 128];
    __shared__ unsigned short wl[64 * 128];
    __shared__ float lsc[128], lsh[128];
    int t = threadIdx.x;
    {   // linear conflict-free staging copy
        const uint4* gh = (const uint4*)wt2h;
        const uint4* gl = (const uint4*)wt2l;
        uint4* dh = (uint4*)wh;
        uint4* dl = (uint4*)wl;
        for (int i = t; i < 1024; i += 512) { dh[i] = gh[i]; dl[i] = gl[i]; }
    }
    if (t < 128) {   // fused bnfinal (sum the 8 interleaved copies)
        double sm = 0.0, qq = 0.0;
#pragma unroll
        for (int cpy = 0; cpy < 8; cpy++) {
            sm += bnacc[cpy * 256 + t];
            qq += bnacc[cpy * 256 + 128 + t];
        }
        double mean = sm / n;
        double var = qq / n - mean * mean;
        float sc = gamma[t] * rsqrtf((float)var + BN_EPS);
        lsc[t] = sc;
        lsh[t] = beta[t] - (float)mean * sc;
    }
    __syncthreads();

    float pa = prelu_a[0];
    int w = t >> 6, l = t & 63;
    int lr = l & 15, lg = l >> 4;
    int rowbase = blockIdx.x * 128;
    int arow = rowbase + w * 16 + lr;
    if (arow >= n) arow = n - 1;

    f32x4 acc[4];
#pragma unroll
    for (int nt = 0; nt < 4; nt++) acc[nt] = (f32x4)(0.0f);

#pragma unroll
    for (int ks = 0; ks < 4; ks++) {
        const uint4* ap = (const uint4*)(zb + (size_t)arow * 64 + ks * 16 + lg * 4);
        uint4 u = ap[0];
        const float4* sc4 = (const float4*)&lsc[ks * 32 + lg * 8];
        const float4* sh4 = (const float4*)&lsh[ks * 32 + lg * 8];
        float4 s0 = sc4[0], s1 = sc4[1];
        float4 t0 = sh4[0], t1 = sh4[1];
        float vv[8];
        vv[0] = fmaf(bf_lo(u.x), s0.x, t0.x); vv[1] = fmaf(bf_hi(u.x), s0.y, t0.y);
        vv[2] = fmaf(bf_lo(u.y), s0.z, t0.z); vv[3] = fmaf(bf_hi(u.y), s0.w, t0.w);
        vv[4] = fmaf(bf_lo(u.z), s1.x, t1.x); vv[5] = fmaf(bf_hi(u.z), s1.y, t1.y);
        vv[6] = fmaf(bf_lo(u.w), s1.z, t1.z); vv[7] = fmaf(bf_hi(u.w), s1.w, t1.w);
        bf16x8 ah, al;
#pragma unroll
        for (int j = 0; j < 8; j++) {
            float y = vv[j] >= 0.f ? vv[j] : pa * vv[j];
            unsigned short hi = f2bf(y);
            ah[j] = (short)hi;
            al[j] = (short)f2bf(y - bf2f(hi));
        }
#pragma unroll
        for (int nt = 0; nt < 4; nt++) {
            int ao = (nt * 16 + lr) * 128 + (((4 * ks + lg) ^ lr) << 3);
            bf16x8 bh = *(const bf16x8*)&wh[ao];
            bf16x8 bl = *(const bf16x8*)&wl[ao];
            acc[nt] = __builtin_amdgcn_mfma_f32_16x16x32_bf16(ah, bh, acc[nt], 0, 0, 0);
            acc[nt] = __builtin_amdgcn_mfma_f32_16x16x32_bf16(al, bh, acc[nt], 0, 0, 0);
            acc[nt] = __builtin_amdgcn_mfma_f32_16x16x32_bf16(ah, bl, acc[nt], 0, 0, 0);
        }
    }
    __syncthreads();
    unsigned short* ob = wh;   // reuse as [128][64] bf16 bounce
#pragma unroll
    for (int r = 0; r < 4; r++) {
        int rl = w * 16 + lg * 4 + r;
        int grow = rowbase + rl;
        float di = dinv[grow < n ? grow : 0];
#pragma unroll
        for (int nt = 0; nt < 4; nt++)
            ob[rl * 64 + nt * 16 + lr] = f2bf(acc[nt][r] * di);
    }
    __syncthreads();
    const unsigned int* ob32 = (const unsigned int*)ob;
    for (int i = t; i < 128 * 32; i += 512) {
        int rl = i >> 5, cu = i & 31;
        int grow = rowbase + rl;
        if (grow < n) h2[(size_t)grow * 32 + cu] = ob32[rl * 32 + cu];
    }
}

// ------------ aggregation 2 -> output (bf16 gather, fp32 out) ------------
// 1 wave/node, 64 lanes x 2B/lane row gather; 16/8/4/1 batched tiers.

__global__ __launch_bounds__(64) void agg2_k(const unsigned short* __restrict__ hs,  // bf16, 64/row
                                             const float* __restrict__ dinv,
                                             const int2* __restrict__ rowspan,
                                             const int* __restrict__ srcs,
                                             const float* __restrict__ b2,
                                             float* __restrict__ out, int n) {
    int nd = blockIdx.x;
    int f = threadIdx.x;
    float di = dinv[nd];
    float acc = bf2f(hs[(size_t)nd * F2 + f]);
    int2 span = rowspan[nd];
    int e = span.x, e1 = span.y;
    for (; e + 16 <= e1; e += 16) {
        int s[16];
#pragma unroll
        for (int j = 0; j < 16; j++) s[j] = srcs[e + j];
        unsigned short v[16];
#pragma unroll
        for (int j = 0; j < 16; j++) v[j] = hs[(size_t)s[j] * F2 + f];
#pragma unroll
        for (int j = 0; j < 16; j++) acc += bf2f(v[j]);
    }
    for (; e + 8 <= e1; e += 8) {
        int s[8];
#pragma unroll
        for (int j = 0; j < 8; j++) s[j] = srcs[e + j];
        unsigned short v[8];
#pragma unroll
        for (int j = 0; j < 8; j++) v[j] = hs[(size_t)s[j] * F2 + f];
#pragma unroll
        for (int j = 0; j < 8; j++) acc += bf2f(v[j]);
    }
    for (; e + 4 <= e1; e += 4) {
        int s[4];
#pragma unroll
        for (int j = 0; j < 4; j++) s[j] = srcs[e + j];
        unsigned short v[4];
#pragma unroll
        for (int j = 0; j < 4; j++) v[j] = hs[(size_t)s[j] * F2 + f];
#pragma unroll
        for (int j = 0; j < 4; j++) acc += bf2f(v[j]);
    }
    for (; e < e1; e++)
        acc += bf2f(hs[(size_t)srcs[e] * F2 + f]);
    float o = fmaf(acc, di, b2[f]);
    __builtin_nontemporal_store(o, out + (size_t)nd * F2 + f);
}

// ---------------- launch ----------------

extern "C" void kernel_launch(void* const* d_in, const int* in_sizes, int n_in,
                              void* d_out, int out_size, void* d_ws, size_t ws_size,
                              hipStream_t stream) {
    const float* x       = (const float*)d_in[0];
    const int*   ei      = (const int*)d_in[1];
    const float* W1      = (const float*)d_in[2];
    const float* b1      = (const float*)d_in[3];
    const float* W2      = (const float*)d_in[4];
    const float* b2      = (const float*)d_in[5];
    const float* gamma   = (const float*)d_in[6];
    const float* beta    = (const float*)d_in[7];
    const float* prelu_a = (const float*)d_in[8];

    const int N = in_sizes[0] / DIN;
    const int E = in_sizes[1] / 2;
    const int* src = ei;
    const int* dst = ei + E;
    const int NBUCK = (N + NODE_BMASK) >> NODE_BSHIFT;  // 391 for N=100000

    char* p = (char*)d_ws;
    size_t off = 0;
    auto take = [&](size_t bytes) -> char* {
        char* r = p + off;
        off = (off + bytes + 255) & ~(size_t)255;
        return r;
    };
    int*            bucketcnt  = (int*)take(512 * 4);            // adjacent to bnacc:
    double*         bnacc      = (double*)take(8 * 256 * 8);     // one merged memset
    float*          dinv       = (float*)take((size_t)N * 4);
    int2*           rowspan    = (int2*)take((size_t)N * 8);
    int*            srcsorted  = (int*)take((size_t)512 * PADB * 4);
    unsigned int*   pairs      = (unsigned int*)take((size_t)512 * PADB * 4);
    unsigned short* wt1h       = (unsigned short*)take(128 * 128 * 2);
    unsigned short* wt1l       = (unsigned short*)take(128 * 128 * 2);
    unsigned short* wt2h       = (unsigned short*)take(64 * 128 * 2);
    unsigned short* wt2l       = (unsigned short*)take(64 * 128 * 2);
    unsigned int*   h          = (unsigned int*)take((size_t)N * 64 * 4);  // bf16 h' (128 feats)
    unsigned int*   z          = (unsigned int*)take((size_t)N * 64 * 4);  // bf16 z (128 feats)
    unsigned int*   h2         = h;   // h dead after agg1; bf16 h2' (64 feats)
    float*          out        = (float*)d_out;

    hipMemsetAsync(bucketcnt, 0, 512 * 4 + 8 * 256 * 8, stream);  // bucketcnt + bnacc

    const int eb = (E + CHUNK - 1) / CHUNK;

    binpass_k<<<eb + 12, 256, 0, stream>>>(src, dst, bucketcnt, pairs, E, eb,
                                           W1, W2, wt1h, wt1l, wt2h, wt2l);
    bucket_k<<<NBUCK, 256, 0, stream>>>(pairs, bucketcnt, dinv, rowspan, srcsorted, N);

    gemm1_k<<<(N + 127) / 128, 512, 0, stream>>>(x, wt1h, wt1l, dinv, h, N);
    const int halfN = N / 2;
    agg1_k<<<halfN, 64, 0, stream>>>(h, dinv, rowspan, srcsorted, b1, z, 0);
    agg1_k<<<N - halfN, 64, 0, stream>>>(h, dinv, rowspan, srcsorted, b1, z, halfN);
    bnstats_k<<<2048, 256, 0, stream>>>(z, bnacc, N);
    gemm2_k<<<(N + 127) / 128, 512, 0, stream>>>(z, wt2h, wt2l, bnacc, gamma, beta, prelu_a, dinv, h2, N);
    agg2_k<<<N, F2, 0, stream>>>((const unsigned short*)h2, dinv, rowspan, srcsorted, b2, out, N);
}

// Round 13
// 294.465 us; speedup vs baseline: 1.0319x; 1.0319x over previous
//
#include <hip/hip_runtime.h>

// GCN forward: conv1(GEMM + sym-norm agg) -> BN -> PReLU -> conv2(GEMM + agg)
// N=100000, E=1600000, DIN=128, 2H=128, H=64. fp32 in/out.
//
// R16 changes vs R15 (303.9, diagnostic) / R14 (295.0):
//  - binpass CHUNK 8192 -> 2048: R15's profile showed binpass_k at 42.6 us
//    with 7% occupancy (196 blocks on 256 CUs; serial 32-iter per-block
//    loops). 782 blocks now (~3/CU). BW floor is ~5 us.
//  - REVERT R15's agg1 split (drain-bubble cost; diagnostic served) and
//    bnstats 2048/8-copy (back to 1024/4-copy) -> exact R14 elsewhere.
// R14 keepers: packed uint pairs + LDS-staged bucket_k, 1-wave-per-node aggs
// with 16/8/4/1 gather tiers, int2 rowspan, bf16 z, fused binpass+wprep,
// swizzled bf16 W tables, MFMA split-precision GEMMs, fused bnfinal, dinv
// pre-scaling, NT stores.

#define DIN 128
#define F1  128   // 2H
#define F2  64    // H
#define BN_EPS 1e-5f
#define NODE_BSHIFT 8          // 256 nodes per bucket
#define NODE_BMASK  255
#define CHUNK 2048             // edges per binpass block (R16: was 8192)
#define PADB 4608              // padded edges per bucket (mean 4096 + 8 sigma)

typedef __attribute__((ext_vector_type(8))) short bf16x8;
typedef __attribute__((ext_vector_type(8))) unsigned short u16x8;
typedef __attribute__((ext_vector_type(4))) float f32x4;
typedef __attribute__((ext_vector_type(2))) float f32x2;

__device__ __forceinline__ unsigned short f2bf(float f) {
    unsigned int u = __float_as_uint(f);
    u = u + 0x7fffu + ((u >> 16) & 1u);   // RNE
    return (unsigned short)(u >> 16);
}
__device__ __forceinline__ float bf2f(unsigned short u) { return __uint_as_float((unsigned int)u << 16); }
__device__ __forceinline__ float bf_lo(unsigned int v) { return __uint_as_float(v << 16); }
__device__ __forceinline__ float bf_hi(unsigned int v) { return __uint_as_float(v & 0xffff0000u); }

// ---------------- graph build + W prep (fused) ----------------
// blocks [0,eb): block counting-sort of 2048-edge chunks into padded
// per-bucket regions (count-based cursors, bucketcnt pre-zeroed).
// pairs entry: src | (dst&255)<<24  (src < 2^17).
// blocks [eb,eb+12): W1/W2 -> swizzled transposed bf16 hi/lo tables.
// addr(c,k) = c*128 + ((k>>3)^(c&15))*8 + (k&7)   (ushort units)

__global__ __launch_bounds__(256) void binpass_k(const int* __restrict__ src,
                                                 const int* __restrict__ dst,
                                                 int* __restrict__ bucketcnt,
                                                 unsigned int* __restrict__ pairs, int e, int eb,
                                                 const float* __restrict__ W1,
                                                 const float* __restrict__ W2,
                                                 unsigned short* __restrict__ wt1h,
                                                 unsigned short* __restrict__ wt1l,
                                                 unsigned short* __restrict__ wt2h,
                                                 unsigned short* __restrict__ wt2l) {
    if (blockIdx.x >= eb) {   // ---- wprep tail blocks ----
        int t = (blockIdx.x - eb) * 256 + threadIdx.x;
        if (t < 2048) {                 // W1: 128 cols x 16 k-octets
            int c = t >> 4, k8 = (t & 15) * 8;
            u16x8 hv, lv;
#pragma unroll
            for (int j = 0; j < 8; j++) {
                float v = W1[(size_t)(k8 + j) * 128 + c];
                unsigned short hi = f2bf(v);
                hv[j] = hi;
                lv[j] = f2bf(v - bf2f(hi));
            }
            int addr = c * 128 + (((k8 >> 3) ^ (c & 15)) << 3);
            *(u16x8*)&wt1h[addr] = hv;
            *(u16x8*)&wt1l[addr] = lv;
        } else if (t < 3072) {          // W2: 64 cols x 16 k-octets
            int tt = t - 2048;
            int c = tt >> 4, k8 = (tt & 15) * 8;
            u16x8 hv, lv;
#pragma unroll
            for (int j = 0; j < 8; j++) {
                float v = W2[(size_t)(k8 + j) * 64 + c];
                unsigned short hi = f2bf(v);
                hv[j] = hi;
                lv[j] = f2bf(v - bf2f(hi));
            }
            int addr = c * 128 + (((k8 >> 3) ^ (c & 15)) << 3);
            *(u16x8*)&wt2h[addr] = hv;
            *(u16x8*)&wt2l[addr] = lv;
        }
        return;
    }
    // ---- binpass body ----
    __shared__ int lh[512], lbase[512], lrank[512];
    int t = threadIdx.x;
    for (int i = t; i < 512; i += 256) { lh[i] = 0; lrank[i] = 0; }
    __syncthreads();
    int base = blockIdx.x * CHUNK;
    int end = base + CHUNK; if (end > e) end = e;
    for (int i = base + t; i < end; i += 256)
        atomicAdd(&lh[dst[i] >> NODE_BSHIFT], 1);
    __syncthreads();
    for (int b = t; b < 512; b += 256) {
        int v = lh[b];
        lbase[b] = v ? (b * PADB + atomicAdd(&bucketcnt[b], v)) : 0;
    }
    __syncthreads();
    for (int i = base + t; i < end; i += 256) {
        int sv = src[i], dv = dst[i];
        int b = dv >> NODE_BSHIFT;
        int r = atomicAdd(&lrank[b], 1);
        int idx = lbase[b] + r;
        if (idx < (b + 1) * PADB)
            pairs[idx] = (unsigned int)sv | ((unsigned int)(dv & NODE_BMASK) << 24);
    }
}

// one block per bucket: LDS-stage packed pairs, per-node degree -> dinv +
// rowspan, fine scatter from LDS.

__global__ __launch_bounds__(256) void bucket_k(const unsigned int* __restrict__ pairs,
                                                const int* __restrict__ bucketcnt,
                                                float* __restrict__ dinv,
                                                int2* __restrict__ rowspan,
                                                int* __restrict__ srcsorted, int n) {
    __shared__ unsigned int lp[PADB];          // 18.4 KB packed pairs
    __shared__ int lh[256], loff[256], lrank[256];
    int b = blockIdx.x, t = threadIdx.x;
    int e0 = b * PADB;
    int cnt = bucketcnt[b];
    lh[t] = 0;
    lrank[t] = 0;
    __syncthreads();
    for (int i = t; i < cnt; i += 256) {
        unsigned int p = pairs[e0 + i];
        lp[i] = p;
        atomicAdd(&lh[p >> 24], 1);
    }
    __syncthreads();
    int deg = lh[t];
    int run = deg;
    for (int ofs = 1; ofs < 256; ofs <<= 1) {
        int y = (t >= ofs) ? lh[t - ofs] : 0;
        __syncthreads();
        run += y;
        lh[t] = run;
        __syncthreads();
    }
    loff[t] = run - deg;
    int node = (b << NODE_BSHIFT) + t;
    if (node < n) {
        dinv[node] = rsqrtf((float)(deg + 1));   // +1 self-loop
        rowspan[node] = make_int2(e0 + (run - deg), e0 + run);
    }
    __syncthreads();
    for (int i = t; i < cnt; i += 256) {
        unsigned int p = lp[i];
        int lo = p >> 24;
        int r = atomicAdd(&lrank[lo], 1);
        srcsorted[e0 + loff[lo] + r] = (int)(p & 0x00FFFFFFu);
    }
}

// ---- GEMM1 (MFMA): h'(bf16) = dinv * (x @ W1), split precision ----
// 128 rows/block, 512 threads (8 waves of 16 rows x 128 cols).

__global__ __launch_bounds__(512) void gemm1_k(const float* __restrict__ x,
                                               const unsigned short* __restrict__ wt1h,
                                               const unsigned short* __restrict__ wt1l,
                                               const float* __restrict__ dinv,
                                               unsigned int* __restrict__ h, int n) {
    __shared__ unsigned short wh[128 * 128];   // W^T hi, swizzled (prebuilt layout)
    __shared__ unsigned short wl[128 * 128];   // W^T lo
    int t = threadIdx.x;
    {   // linear conflict-free staging copy (L2-hot source)
        const uint4* gh = (const uint4*)wt1h;
        const uint4* gl = (const uint4*)wt1l;
        uint4* dh = (uint4*)wh;
        uint4* dl = (uint4*)wl;
        for (int i = t; i < 2048; i += 512) { dh[i] = gh[i]; dl[i] = gl[i]; }
    }
    __syncthreads();

    int w = t >> 6, l = t & 63;
    int lr = l & 15, lg = l >> 4;
    int rowbase = blockIdx.x * 128;
    int arow = rowbase + w * 16 + lr;
    if (arow >= n) arow = n - 1;

    f32x4 acc[8];
#pragma unroll
    for (int nt = 0; nt < 8; nt++) acc[nt] = (f32x4)(0.0f);

#pragma unroll
    for (int ks = 0; ks < 4; ks++) {
        const float4* ap = (const float4*)(x + (size_t)arow * 128 + ks * 32 + lg * 8);
        float4 v0 = ap[0], v1 = ap[1];
        float vv[8] = {v0.x, v0.y, v0.z, v0.w, v1.x, v1.y, v1.z, v1.w};
        bf16x8 ah, al;
#pragma unroll
        for (int j = 0; j < 8; j++) {
            unsigned short hi = f2bf(vv[j]);
            ah[j] = (short)hi;
            al[j] = (short)f2bf(vv[j] - bf2f(hi));
        }
#pragma unroll
        for (int nt = 0; nt < 8; nt++) {
            int ao = (nt * 16 + lr) * 128 + (((4 * ks + lg) ^ lr) << 3);
            bf16x8 bh = *(const bf16x8*)&wh[ao];
            bf16x8 bl = *(const bf16x8*)&wl[ao];
            acc[nt] = __builtin_amdgcn_mfma_f32_16x16x32_bf16(ah, bh, acc[nt], 0, 0, 0);
            acc[nt] = __builtin_amdgcn_mfma_f32_16x16x32_bf16(al, bh, acc[nt], 0, 0, 0);
            acc[nt] = __builtin_amdgcn_mfma_f32_16x16x32_bf16(ah, bl, acc[nt], 0, 0, 0);
        }
    }
    __syncthreads();                       // all waves done reading W
    unsigned short* ob = wh;               // reuse as [128][128] bf16 bounce
#pragma unroll
    for (int r = 0; r < 4; r++) {
        int rl = w * 16 + lg * 4 + r;      // C row = (lane>>4)*4 + reg
        int grow = rowbase + rl;
        float di = dinv[grow < n ? grow : 0];
#pragma unroll
        for (int nt = 0; nt < 8; nt++)
            ob[rl * 128 + nt * 16 + lr] = f2bf(acc[nt][r] * di);
    }
    __syncthreads();
    const unsigned int* ob32 = (const unsigned int*)ob;
    for (int i = t; i < 128 * 64; i += 512) {
        int rl = i >> 6, cu = i & 63;
        int grow = rowbase + rl;
        if (grow < n) h[(size_t)grow * 64 + cu] = ob32[rl * 64 + cu];
    }
}

// -------- aggregation 1: z(bf16) = dinv_d * (sum h'_s + h'_d) + b1 --------
// 1 wave/node, 64 lanes x 4B/lane row gather; 16/8/4/1 batched tiers.

__global__ __launch_bounds__(64) void agg1_k(const unsigned int* __restrict__ h,  // bf16x2, 64/row
                                             const float* __restrict__ dinv,
                                             const int2* __restrict__ rowspan,
                                             const int* __restrict__ srcs,
                                             const float* __restrict__ b1,
                                             unsigned int* __restrict__ z, int n) {
    int nd = blockIdx.x;
    int f = threadIdx.x;  // bf16-pair index, 0..63
    float di = dinv[nd];
    unsigned int sv = h[(size_t)nd * 64 + f];
    float ax = bf_lo(sv);
    float ay = bf_hi(sv);
    int2 span = rowspan[nd];
    int e = span.x, e1 = span.y;
    for (; e + 16 <= e1; e += 16) {
        int s[16];
#pragma unroll
        for (int j = 0; j < 16; j++) s[j] = srcs[e + j];
        unsigned int v[16];
#pragma unroll
        for (int j = 0; j < 16; j++) v[j] = h[(size_t)s[j] * 64 + f];
#pragma unroll
        for (int j = 0; j < 16; j++) { ax += bf_lo(v[j]); ay += bf_hi(v[j]); }
    }
    for (; e + 8 <= e1; e += 8) {
        int s[8];
#pragma unroll
        for (int j = 0; j < 8; j++) s[j] = srcs[e + j];
        unsigned int v[8];
#pragma unroll
        for (int j = 0; j < 8; j++) v[j] = h[(size_t)s[j] * 64 + f];
#pragma unroll
        for (int j = 0; j < 8; j++) { ax += bf_lo(v[j]); ay += bf_hi(v[j]); }
    }
    for (; e + 4 <= e1; e += 4) {
        int s[4];
#pragma unroll
        for (int j = 0; j < 4; j++) s[j] = srcs[e + j];
        unsigned int v[4];
#pragma unroll
        for (int j = 0; j < 4; j++) v[j] = h[(size_t)s[j] * 64 + f];
#pragma unroll
        for (int j = 0; j < 4; j++) { ax += bf_lo(v[j]); ay += bf_hi(v[j]); }
    }
    for (; e < e1; e++) {
        unsigned int v = h[(size_t)srcs[e] * 64 + f];
        ax += bf_lo(v);
        ay += bf_hi(v);
    }
    float2 bb = ((const float2*)b1)[f];
    float ox = fmaf(ax, di, bb.x);
    float oy = fmaf(ay, di, bb.y);
    unsigned int zu = (unsigned int)f2bf(ox) | ((unsigned int)f2bf(oy) << 16);
    __builtin_nontemporal_store(zu, z + (size_t)nd * 64 + f);
}

// ---------------- BatchNorm stats (bf16 z input) ----------------

__global__ __launch_bounds__(256) void bnstats_k(const unsigned int* __restrict__ zb,
                                                 double* __restrict__ bnacc, int n) {
    __shared__ float reds[8][128];
    __shared__ float redq[8][128];
    int t = threadIdx.x;
    int q = t >> 5;          // row lane 0..7
    int c = t & 31;          // uint2 column (4 feats)
    const uint2* z2 = (const uint2*)zb;
    float s0 = 0.f, s1 = 0.f, s2 = 0.f, s3 = 0.f;
    float q0 = 0.f, q1 = 0.f, q2 = 0.f, q3 = 0.f;
    int stride = gridDim.x * 8;
#pragma unroll 2
    for (int r = blockIdx.x * 8 + q; r < n; r += stride) {
        uint2 v = z2[(size_t)r * 32 + c];
        float a = bf_lo(v.x), b = bf_hi(v.x), cc = bf_lo(v.y), d = bf_hi(v.y);
        s0 += a; s1 += b; s2 += cc; s3 += d;
        q0 = fmaf(a, a, q0);
        q1 = fmaf(b, b, q1);
        q2 = fmaf(cc, cc, q2);
        q3 = fmaf(d, d, q3);
    }
    reds[q][c * 4]     = s0; redq[q][c * 4]     = q0;
    reds[q][c * 4 + 1] = s1; redq[q][c * 4 + 1] = q1;
    reds[q][c * 4 + 2] = s2; redq[q][c * 4 + 2] = q2;
    reds[q][c * 4 + 3] = s3; redq[q][c * 4 + 3] = q3;
    __syncthreads();
    if (t < 128) {
        float ssum = 0.f, qsum = 0.f;
#pragma unroll
        for (int i = 0; i < 8; i++) {
            ssum += reds[i][t];
            qsum += redq[i][t];
        }
        int copy = (blockIdx.x & 3) * 256;
        atomicAdd(&bnacc[copy + t], (double)ssum);
        atomicAdd(&bnacc[copy + 128 + t], (double)qsum);
    }
}

// ---- GEMM2 (MFMA): h2'(bf16) = dinv * (prelu(bn(z)) @ W2), bnfinal fused ----
// z input bf16 (uint = 2 feats); BN/PReLU in fp32; full hi/lo MFMA split.

__global__ __launch_bounds__(512) void gemm2_k(const unsigned int* __restrict__ zb,
                                               const unsigned short* __restrict__ wt2h,
                                               const unsigned short* __restrict__ wt2l,
                                               const double* __restrict__ bnacc, // 4 copies x 256
                                               const float* __restrict__ gamma,
                                               const float* __restrict__ beta,
                                               const float* __restrict__ prelu_a,
                                               const float* __restrict__ dinv,
                                               unsigned int* __restrict__ h2, int n) {
    __shared__ unsigned short wh[64 * 128];
    __shared__ unsigned short wl[64 * 128];
    __shared__ float lsc[128], lsh[128];
    int t = threadIdx.x;
    {   // linear conflict-free staging copy
        const uint4* gh = (const uint4*)wt2h;
        const uint4* gl = (const uint4*)wt2l;
        uint4* dh = (uint4*)wh;
        uint4* dl = (uint4*)wl;
        for (int i = t; i < 1024; i += 512) { dh[i] = gh[i]; dl[i] = gl[i]; }
    }
    if (t < 128) {   // fused bnfinal (sum the 4 interleaved copies)
        double sm = 0.0, qq = 0.0;
#pragma unroll
        for (int cpy = 0; cpy < 4; cpy++) {
            sm += bnacc[cpy * 256 + t];
            qq += bnacc[cpy * 256 + 128 + t];
        }
        double mean = sm / n;
        double var = qq / n - mean * mean;
        float sc = gamma[t] * rsqrtf((float)var + BN_EPS);
        lsc[t] = sc;
        lsh[t] = beta[t] - (float)mean * sc;
    }
    __syncthreads();

    float pa = prelu_a[0];
    int w = t >> 6, l = t & 63;
    int lr = l & 15, lg = l >> 4;
    int rowbase = blockIdx.x * 128;
    int arow = rowbase + w * 16 + lr;
    if (arow >= n) arow = n - 1;

    f32x4 acc[4];
#pragma unroll
    for (int nt = 0; nt < 4; nt++) acc[nt] = (f32x4)(0.0f);

#pragma unroll
    for (int ks = 0; ks < 4; ks++) {
        const uint4* ap = (const uint4*)(zb + (size_t)arow * 64 + ks * 16 + lg * 4);
        uint4 u = ap[0];
        const float4* sc4 = (const float4*)&lsc[ks * 32 + lg * 8];
        const float4* sh4 = (const float4*)&lsh[ks * 32 + lg * 8];
        float4 s0 = sc4[0], s1 = sc4[1];
        float4 t0 = sh4[0], t1 = sh4[1];
        float vv[8];
        vv[0] = fmaf(bf_lo(u.x), s0.x, t0.x); vv[1] = fmaf(bf_hi(u.x), s0.y, t0.y);
        vv[2] = fmaf(bf_lo(u.y), s0.z, t0.z); vv[3] = fmaf(bf_hi(u.y), s0.w, t0.w);
        vv[4] = fmaf(bf_lo(u.z), s1.x, t1.x); vv[5] = fmaf(bf_hi(u.z), s1.y, t1.y);
        vv[6] = fmaf(bf_lo(u.w), s1.z, t1.z); vv[7] = fmaf(bf_hi(u.w), s1.w, t1.w);
        bf16x8 ah, al;
#pragma unroll
        for (int j = 0; j < 8; j++) {
            float y = vv[j] >= 0.f ? vv[j] : pa * vv[j];
            unsigned short hi = f2bf(y);
            ah[j] = (short)hi;
            al[j] = (short)f2bf(y - bf2f(hi));
        }
#pragma unroll
        for (int nt = 0; nt < 4; nt++) {
            int ao = (nt * 16 + lr) * 128 + (((4 * ks + lg) ^ lr) << 3);
            bf16x8 bh = *(const bf16x8*)&wh[ao];
            bf16x8 bl = *(const bf16x8*)&wl[ao];
            acc[nt] = __builtin_amdgcn_mfma_f32_16x16x32_bf16(ah, bh, acc[nt], 0, 0, 0);
            acc[nt] = __builtin_amdgcn_mfma_f32_16x16x32_bf16(al, bh, acc[nt], 0, 0, 0);
            acc[nt] = __builtin_amdgcn_mfma_f32_16x16x32_bf16(ah, bl, acc[nt], 0, 0, 0);
        }
    }
    __syncthreads();
    unsigned short* ob = wh;   // reuse as [128][64] bf16 bounce
#pragma unroll
    for (int r = 0; r < 4; r++) {
        int rl = w * 16 + lg * 4 + r;
        int grow = rowbase + rl;
        float di = dinv[grow < n ? grow : 0];
#pragma unroll
        for (int nt = 0; nt < 4; nt++)
            ob[rl * 64 + nt * 16 + lr] = f2bf(acc[nt][r] * di);
    }
    __syncthreads();
    const unsigned int* ob32 = (const unsigned int*)ob;
    for (int i = t; i < 128 * 32; i += 512) {
        int rl = i >> 5, cu = i & 31;
        int grow = rowbase + rl;
        if (grow < n) h2[(size_t)grow * 32 + cu] = ob32[rl * 32 + cu];
    }
}

// ------------ aggregation 2 -> output (bf16 gather, fp32 out) ------------
// 1 wave/node, 64 lanes x 2B/lane row gather; 16/8/4/1 batched tiers.

__global__ __launch_bounds__(64) void agg2_k(const unsigned short* __restrict__ hs,  // bf16, 64/row
                                             const float* __restrict__ dinv,
                                             const int2* __restrict__ rowspan,
                                             const int* __restrict__ srcs,
                                             const float* __restrict__ b2,
                                             float* __restrict__ out, int n) {
    int nd = blockIdx.x;
    int f = threadIdx.x;
    float di = dinv[nd];
    float acc = bf2f(hs[(size_t)nd * F2 + f]);
    int2 span = rowspan[nd];
    int e = span.x, e1 = span.y;
    for (; e + 16 <= e1; e += 16) {
        int s[16];
#pragma unroll
        for (int j = 0; j < 16; j++) s[j] = srcs[e + j];
        unsigned short v[16];
#pragma unroll
        for (int j = 0; j < 16; j++) v[j] = hs[(size_t)s[j] * F2 + f];
#pragma unroll
        for (int j = 0; j < 16; j++) acc += bf2f(v[j]);
    }
    for (; e + 8 <= e1; e += 8) {
        int s[8];
#pragma unroll
        for (int j = 0; j < 8; j++) s[j] = srcs[e + j];
        unsigned short v[8];
#pragma unroll
        for (int j = 0; j < 8; j++) v[j] = hs[(size_t)s[j] * F2 + f];
#pragma unroll
        for (int j = 0; j < 8; j++) acc += bf2f(v[j]);
    }
    for (; e + 4 <= e1; e += 4) {
        int s[4];
#pragma unroll
        for (int j = 0; j < 4; j++) s[j] = srcs[e + j];
        unsigned short v[4];
#pragma unroll
        for (int j = 0; j < 4; j++) v[j] = hs[(size_t)s[j] * F2 + f];
#pragma unroll
        for (int j = 0; j < 4; j++) acc += bf2f(v[j]);
    }
    for (; e < e1; e++)
        acc += bf2f(hs[(size_t)srcs[e] * F2 + f]);
    float o = fmaf(acc, di, b2[f]);
    __builtin_nontemporal_store(o, out + (size_t)nd * F2 + f);
}

// ---------------- launch ----------------

extern "C" void kernel_launch(void* const* d_in, const int* in_sizes, int n_in,
                              void* d_out, int out_size, void* d_ws, size_t ws_size,
                              hipStream_t stream) {
    const float* x       = (const float*)d_in[0];
    const int*   ei      = (const int*)d_in[1];
    const float* W1      = (const float*)d_in[2];
    const float* b1      = (const float*)d_in[3];
    const float* W2      = (const float*)d_in[4];
    const float* b2      = (const float*)d_in[5];
    const float* gamma   = (const float*)d_in[6];
    const float* beta    = (const float*)d_in[7];
    const float* prelu_a = (const float*)d_in[8];

    const int N = in_sizes[0] / DIN;
    const int E = in_sizes[1] / 2;
    const int* src = ei;
    const int* dst = ei + E;
    const int NBUCK = (N + NODE_BMASK) >> NODE_BSHIFT;  // 391 for N=100000

    char* p = (char*)d_ws;
    size_t off = 0;
    auto take = [&](size_t bytes) -> char* {
        char* r = p + off;
        off = (off + bytes + 255) & ~(size_t)255;
        return r;
    };
    int*            bucketcnt  = (int*)take(512 * 4);            // adjacent to bnacc:
    double*         bnacc      = (double*)take(4 * 256 * 8);     // one merged memset
    float*          dinv       = (float*)take((size_t)N * 4);
    int2*           rowspan    = (int2*)take((size_t)N * 8);
    int*            srcsorted  = (int*)take((size_t)512 * PADB * 4);
    unsigned int*   pairs      = (unsigned int*)take((size_t)512 * PADB * 4);
    unsigned short* wt1h       = (unsigned short*)take(128 * 128 * 2);
    unsigned short* wt1l       = (unsigned short*)take(128 * 128 * 2);
    unsigned short* wt2h       = (unsigned short*)take(64 * 128 * 2);
    unsigned short* wt2l       = (unsigned short*)take(64 * 128 * 2);
    unsigned int*   h          = (unsigned int*)take((size_t)N * 64 * 4);  // bf16 h' (128 feats)
    unsigned int*   z          = (unsigned int*)take((size_t)N * 64 * 4);  // bf16 z (128 feats)
    unsigned int*   h2         = h;   // h dead after agg1; bf16 h2' (64 feats)
    float*          out        = (float*)d_out;

    hipMemsetAsync(bucketcnt, 0, 512 * 4 + 4 * 256 * 8, stream);  // bucketcnt + bnacc

    const int eb = (E + CHUNK - 1) / CHUNK;

    binpass_k<<<eb + 12, 256, 0, stream>>>(src, dst, bucketcnt, pairs, E, eb,
                                           W1, W2, wt1h, wt1l, wt2h, wt2l);
    bucket_k<<<NBUCK, 256, 0, stream>>>(pairs, bucketcnt, dinv, rowspan, srcsorted, N);

    gemm1_k<<<(N + 127) / 128, 512, 0, stream>>>(x, wt1h, wt1l, dinv, h, N);
    agg1_k<<<N, 64, 0, stream>>>(h, dinv, rowspan, srcsorted, b1, z, N);
    bnstats_k<<<1024, 256, 0, stream>>>(z, bnacc, N);
    gemm2_k<<<(N + 127) / 128, 512, 0, stream>>>(z, wt2h, wt2l, bnacc, gamma, beta, prelu_a, dinv, h2, N);
    agg2_k<<<N, F2, 0, stream>>>((const unsigned short*)h2, dinv, rowspan, srcsorted, b2, out, N);
}